// Round 1
// baseline (303.947 us; speedup 1.0000x reference)
//
#include <hip/hip_runtime.h>
#include <hip/hip_bf16.h>
#include <stdint.h>

typedef __bf16 bf16_t;
typedef __bf16 bf16x8 __attribute__((ext_vector_type(8)));
typedef float f32x4 __attribute__((ext_vector_type(4)));

#define B_  8
#define S_  1024
#define D_  1024
#define H_  16
#define DH_ 64

static __device__ __forceinline__ f32x4 mfma_bf16(bf16x8 a, bf16x8 b, f32x4 c) {
  return __builtin_amdgcn_mfma_f32_16x16x32_bf16(a, b, c, 0, 0, 0);
}

// async global->LDS, 16 bytes per lane; LDS dest = wave-uniform base + lane*16
#define GLOAD_LDS16(g, l)                                                     \
  __builtin_amdgcn_global_load_lds(                                           \
      (const __attribute__((address_space(1))) void*)(g),                     \
      (__attribute__((address_space(3))) void*)(l), 16, 0, 0)

// ---------------------------------------------------------------------------
// Transpose four 1024x1024 f32 weights -> bf16 transposed: Wt[n][k] = W[k][n]
// grid (16,16,4), block 256
// ---------------------------------------------------------------------------
__global__ __launch_bounds__(256) void transpose4(
    const float* __restrict__ w0, const float* __restrict__ w1,
    const float* __restrict__ w2, const float* __restrict__ w3,
    bf16_t* __restrict__ t0, bf16_t* __restrict__ t1,
    bf16_t* __restrict__ t2, bf16_t* __restrict__ t3)
{
  __shared__ float tile[64][65];
  const float* src; bf16_t* dst;
  switch (blockIdx.z) {
    case 0: src = w0; dst = t0; break;
    case 1: src = w1; dst = t1; break;
    case 2: src = w2; dst = t2; break;
    default: src = w3; dst = t3; break;
  }
  const int tx = threadIdx.x & 63;
  const int ty = threadIdx.x >> 6;
  const int c0 = blockIdx.x * 64, r0 = blockIdx.y * 64;
#pragma unroll
  for (int r = ty; r < 64; r += 4)
    tile[r][tx] = src[(size_t)(r0 + r) * 1024 + c0 + tx];
  __syncthreads();
#pragma unroll
  for (int r = ty; r < 64; r += 4)
    dst[(size_t)(c0 + r) * 1024 + r0 + tx] = (bf16_t)tile[tx][r];
}

// ---------------------------------------------------------------------------
// Convert Q/K/V f32 -> bf16 (contiguous). grid (4096,3), block 256, 8 elem/thr.
// ---------------------------------------------------------------------------
__global__ __launch_bounds__(256) void convert_qkv(
    const float* __restrict__ q, const float* __restrict__ k,
    const float* __restrict__ v,
    bf16_t* __restrict__ qo, bf16_t* __restrict__ ko, bf16_t* __restrict__ vo)
{
  const float* src; bf16_t* dst;
  switch (blockIdx.y) {
    case 0: src = q; dst = qo; break;
    case 1: src = k; dst = ko; break;
    default: src = v; dst = vo; break;
  }
  const size_t i = ((size_t)blockIdx.x * 256 + threadIdx.x) * 8;
  float4 a = *(const float4*)(src + i);
  float4 b = *(const float4*)(src + i + 4);
  bf16x8 o;
  o[0] = (bf16_t)a.x; o[1] = (bf16_t)a.y; o[2] = (bf16_t)a.z; o[3] = (bf16_t)a.w;
  o[4] = (bf16_t)b.x; o[5] = (bf16_t)b.y; o[6] = (bf16_t)b.z; o[7] = (bf16_t)b.w;
  *(bf16x8*)(dst + i) = o;
}

// ---------------------------------------------------------------------------
// Transpose V: [B,H,S,64] -> [B,H,64,S].  grid (16, 128): x=s-tile, y=b*H+h.
// ---------------------------------------------------------------------------
__global__ __launch_bounds__(256) void transposeV(
    const bf16_t* __restrict__ src, bf16_t* __restrict__ dst)
{
  __shared__ bf16_t t[64 * 72];     // row stride 72 elems (144B, 16B-aligned)
  const size_t base = (size_t)blockIdx.y * (64 * 1024);
  const int s0 = blockIdx.x * 64;
#pragma unroll
  for (int it = 0; it < 2; ++it) {
    const int c = it * 256 + threadIdx.x;
    const int r = c >> 3, col8 = (c & 7) * 8;
    bf16x8 v = *(const bf16x8*)(src + base + (size_t)(s0 + r) * 64 + col8);
    *(bf16x8*)(t + r * 72 + col8) = v;
  }
  __syncthreads();
#pragma unroll
  for (int it = 0; it < 2; ++it) {
    const int c = it * 256 + threadIdx.x;
    const int d = c >> 3, sc8 = (c & 7) * 8;
    bf16x8 v;
#pragma unroll
    for (int j = 0; j < 8; ++j) v[j] = t[(sc8 + j) * 72 + d];
    *(bf16x8*)(dst + base + (size_t)d * 1024 + s0 + sc8) = v;
  }
}

// ---------------------------------------------------------------------------
// Pipelined GEMM core (T2+T3+T4+T5): C = A[M,K](bf16) @ Bt[N,K](bf16)^T
//   BM=256, BN=128, BK=64; 512 thr = 8 waves (4M x 2N), 64x64 out per wave.
//   3-stage LDS pipeline (144 KB dynamic), counted s_waitcnt vmcnt(12)
//   (never drains to 0 in the main loop); XOR slot-swizzle (slot ^= row&7)
//   applied as inverse-swizzled GLOBAL source + swizzled ds_read (rule #21),
//   giving conflict-free ds_read_b128 (8-clk LDS floor).
//   Grid: x = tile id; tileN = x%8 -> each XCD owns one 256KB B panel (L2).
//   M=8192,N=1024 -> 256 tiles/GEMM = exactly 1 full round of 256 CUs.
// MODE: 0 = C f32 row-major; 1 = C bf16 scatter into [B,H,S,64].
// ---------------------------------------------------------------------------
#define BM_G 256
#define BN_G 128
#define BK_G 64
#define KDIM 1024
#define NK_G (KDIM / BK_G)                  // 16
#define ATILE (BM_G * BK_G)                 // 16384 elems (32 KB)
#define BTILE (BN_G * BK_G)                 // 8192 elems  (16 KB)
#define LDS_BYTES ((3 * (ATILE + BTILE)) * 2)  // 147456 B

template <int MODE>
__device__ __forceinline__ void gemm_core(
    const bf16_t* __restrict__ Ap, const bf16_t* __restrict__ Bp,
    void* __restrict__ Cp, bf16_t* smem)
{
  bf16_t* const As = smem;                  // 3 * ATILE
  bf16_t* const Bs = smem + 3 * ATILE;      // 3 * BTILE

  const int tid  = threadIdx.x;
  const int wv   = tid >> 6;
  const int lane = tid & 63;
  const int wm   = wv >> 1;                 // 0..3  (M position)
  const int wn   = wv & 1;                  // 0..1  (N position)
  const int quad = lane >> 4;
  const int l15  = lane & 15;

  const int tileN = blockIdx.x & 7;         // XCD = linear%8 -> one B panel/XCD
  const int tileM = blockIdx.x >> 3;

  // --- staging addressing -------------------------------------------------
  // Each GLOAD line: 512 thr x 16B = 8KB = 64 rows x 128B. Wave wv covers
  // rows [base + wv*8, +8); lane l -> row +(l>>3), LDS 16B-slot (l&7).
  // Inverse swizzle on the global side: slot s holds global slot s^(row&7).
  const int lr  = lane >> 3;                        // row within 8-row group
  const int swz = (((lane & 7) ^ lr) << 3);         // swizzled col (elems)
  const bf16_t* gA0 = Ap + (size_t)(tileM * BM_G + wv * 8 + lr) * KDIM + swz;
  const bf16_t* gB0 = Bp + (size_t)(tileN * BN_G + wv * 8 + lr) * KDIM + swz;
  const int lA0 = wv * 8 * BK_G;                    // wave-uniform LDS elems
  const int lB0 = wv * 8 * BK_G;

#define STAGE_TILE(koff, bA, bB) do {                                          \
    GLOAD_LDS16(gA0 + (koff),                       As + (bA) + lA0);          \
    GLOAD_LDS16(gA0 + (size_t)64  * KDIM + (koff),  As + (bA) + lA0 + 64*BK_G); \
    GLOAD_LDS16(gA0 + (size_t)128 * KDIM + (koff),  As + (bA) + lA0 + 128*BK_G);\
    GLOAD_LDS16(gA0 + (size_t)192 * KDIM + (koff),  As + (bA) + lA0 + 192*BK_G);\
    GLOAD_LDS16(gB0 + (koff),                       Bs + (bB) + lB0);          \
    GLOAD_LDS16(gB0 + (size_t)64  * KDIM + (koff),  Bs + (bB) + lB0 + 64*BK_G); \
  } while (0)

  f32x4 acc[4][4];
#pragma unroll
  for (int mi = 0; mi < 4; ++mi)
#pragma unroll
    for (int ni = 0; ni < 4; ++ni)
      acc[mi][ni] = (f32x4){0.f, 0.f, 0.f, 0.f};

  // prologue: tiles 0,1 -> bufs 0,1 (12 loads in flight)
  STAGE_TILE(0, 0, 0);
  STAGE_TILE(BK_G, ATILE, BTILE);

  int cbA = 0, cbB = 0;                    // compute-buffer elem offsets
  int sbA = 2 * ATILE, sbB = 2 * BTILE;    // stage-buffer elem offsets

  for (int t = 0; t < NK_G; ++t) {
    // stage tile t+2 into the buffer whose reads finished last iteration
    if (t + 2 < NK_G) STAGE_TILE((size_t)(t + 2) * BK_G, sbA, sbB);

    // counted wait: only tile t's 6 loads must land; t+1/t+2 stay in flight
    if (t < NK_G - 2)       asm volatile("s_waitcnt vmcnt(12)" ::: "memory");
    else if (t == NK_G - 2) asm volatile("s_waitcnt vmcnt(6)" ::: "memory");
    else                    asm volatile("s_waitcnt vmcnt(0)" ::: "memory");
    __builtin_amdgcn_s_barrier();
    asm volatile("" ::: "memory");         // no LDS-read hoist above barrier

    // frag reads: swizzled slot = (quad+4*kk) ^ (row&7); row&7 == l15&7
    bf16x8 af[2][4], bfr[2][4];
#pragma unroll
    for (int kk = 0; kk < 2; ++kk) {
      const int sl = (((quad + (kk << 2)) ^ (l15 & 7)) << 3);
#pragma unroll
      for (int mi = 0; mi < 4; ++mi)
        af[kk][mi] = *(const bf16x8*)(As + cbA + (wm * 64 + mi * 16 + l15) * BK_G + sl);
#pragma unroll
      for (int ni = 0; ni < 4; ++ni)
        bfr[kk][ni] = *(const bf16x8*)(Bs + cbB + (wn * 64 + ni * 16 + l15) * BK_G + sl);
    }
    __builtin_amdgcn_s_setprio(1);
#pragma unroll
    for (int kk = 0; kk < 2; ++kk)
#pragma unroll
      for (int mi = 0; mi < 4; ++mi)
#pragma unroll
        for (int ni = 0; ni < 4; ++ni)
          acc[mi][ni] = mfma_bf16(af[kk][mi], bfr[kk][ni], acc[mi][ni]);
    __builtin_amdgcn_s_setprio(0);

    asm volatile("" ::: "memory");         // no LDS-read sink below barrier
    __builtin_amdgcn_s_barrier();          // buf safe to overwrite next iter

    cbA += ATILE; if (cbA == 3 * ATILE) cbA = 0;
    cbB += BTILE; if (cbB == 3 * BTILE) cbB = 0;
    sbA += ATILE; if (sbA == 3 * ATILE) sbA = 0;
    sbB += BTILE; if (sbB == 3 * BTILE) sbB = 0;
  }
#undef STAGE_TILE

  // epilogue: C/D frag layout col=l15(N), row=quad*4+r(M)
#pragma unroll
  for (int mi = 0; mi < 4; ++mi) {
#pragma unroll
    for (int ni = 0; ni < 4; ++ni) {
#pragma unroll
      for (int r = 0; r < 4; ++r) {
        const int row = tileM * BM_G + wm * 64 + mi * 16 + quad * 4 + r;
        const int col = tileN * BN_G + wn * 64 + ni * 16 + l15;
        if (MODE == 0) {
          ((float*)Cp)[(size_t)row * 1024 + col] = acc[mi][ni][r];
        } else {
          const int b = row >> 10, s = row & 1023;
          const int h = col >> 6,  d = col & 63;
          ((bf16_t*)Cp)[(((size_t)(b * H_ + h) << 10) | s) * DH_ + d] =
              (bf16_t)acc[mi][ni][r];
        }
      }
    }
  }
}

// Projection GEMM: z selects {A,B,C}. grid (256,1,3), block 512, 144KB dyn LDS.
__global__ __launch_bounds__(512, 2) void gemm_proj(
    const bf16_t* __restrict__ A0, const bf16_t* __restrict__ A1, const bf16_t* __restrict__ A2,
    const bf16_t* __restrict__ B0, const bf16_t* __restrict__ B1, const bf16_t* __restrict__ B2,
    bf16_t* __restrict__ C0, bf16_t* __restrict__ C1, bf16_t* __restrict__ C2)
{
  extern __shared__ bf16_t smem[];
  const bf16_t* Ap; const bf16_t* Bp; bf16_t* Cp;
  if (blockIdx.z == 0)      { Ap = A0; Bp = B0; Cp = C0; }
  else if (blockIdx.z == 1) { Ap = A1; Bp = B1; Cp = C1; }
  else                      { Ap = A2; Bp = B2; Cp = C2; }
  gemm_core<1>(Ap, Bp, (void*)Cp, smem);
}

// Output GEMM: f32 row-major C. grid (256,1,1), block 512, 144KB dyn LDS.
__global__ __launch_bounds__(512, 2) void gemm_out(
    const bf16_t* __restrict__ Ap, const bf16_t* __restrict__ Bp,
    float* __restrict__ Cp)
{
  extern __shared__ bf16_t smem[];
  gemm_core<0>(Ap, Bp, (void*)Cp, smem);
}

// ---------------------------------------------------------------------------
// Flash attention v4: m97-shaped block-cooperative K-loop. (unchanged)
// ---------------------------------------------------------------------------
__global__ __launch_bounds__(256) void attn64(
    const bf16_t* __restrict__ Q,
    const bf16_t* __restrict__ Kv,
    const bf16_t* __restrict__ Vt,
    const int* __restrict__ valid_lens,
    bf16_t* __restrict__ O)
{
  const int h  = blockIdx.x;
  const int qt = blockIdx.y;
  const int b  = blockIdx.z;
  const int tid  = threadIdx.x;
  const int wave = tid >> 6;
  const int lane = tid & 63;
  const int quad = lane >> 4;
  const int l15  = lane & 15;

  const int L   = valid_lens[b];
  const int nkt = (L + 63) >> 6;

  const size_t base = ((size_t)(b * H_ + h)) * S_ * DH_;
  const bf16_t* Qp = Q  + base;
  const bf16_t* Kp = Kv + base;
  const bf16_t* Vp = Vt + base;     // [64][1024] per (b,h)

  __shared__ bf16_t KsA[64 * 32];   // K tile, d 0..31   [key][d]
  __shared__ bf16_t KsB[64 * 32];   // K tile, d 32..63
  __shared__ bf16_t VsA[64 * 32];   // V^T tile, keys 0..31  [d][key]
  __shared__ bf16_t VsB[64 * 32];   // V^T tile, keys 32..63
  __shared__ bf16_t Pb[4][16 * 72]; // per-wave P [q][key]
  bf16_t* const Pw = &Pb[wave][0];

  const int sr = tid >> 2;
  const int sj = (tid & 3) << 3;
  const int ldsOff = (wave * 64) * 8;      // wave-uniform LDS base offset

  const int qrow = qt * 64 + wave * 16 + l15;
  const bf16x8 qf0 = *(const bf16x8*)(Qp + (size_t)qrow * DH_ + quad * 8);
  const bf16x8 qf1 = *(const bf16x8*)(Qp + (size_t)qrow * DH_ + 32 + quad * 8);

  f32x4 o[4];
  float lsum[4];
#pragma unroll
  for (int r = 0; r < 4; ++r) {
    o[r] = (f32x4){0.f, 0.f, 0.f, 0.f};
    lsum[r] = 0.f;
  }

  for (int kt = 0; kt < nkt; ++kt) {
    const int k0 = kt * 64;

    __syncthreads();   // prior tile's LDS reads complete
    GLOAD_LDS16(Kp + (size_t)(k0 + sr) * DH_ + sj,      KsA + ldsOff);
    GLOAD_LDS16(Kp + (size_t)(k0 + sr) * DH_ + 32 + sj, KsB + ldsOff);
    GLOAD_LDS16(Vp + (size_t)sr * S_ + k0 + sj,         VsA + ldsOff);
    GLOAD_LDS16(Vp + (size_t)sr * S_ + k0 + 32 + sj,    VsB + ldsOff);
    __syncthreads();   // staging drained

    // ---- scores: S = Q K^T ----
    f32x4 sc[4];
#pragma unroll
    for (int n16 = 0; n16 < 4; ++n16) {
      const int row = (n16 * 16 + l15) * 32 + quad * 8;
      bf16x8 kf0 = *(const bf16x8*)(KsA + row);
      bf16x8 kf1 = *(const bf16x8*)(KsB + row);
      f32x4 s = (f32x4){0.f, 0.f, 0.f, 0.f};
      s = mfma_bf16(qf0, kf0, s);
      s = mfma_bf16(qf1, kf1, s);
      sc[n16] = s;
    }

    // ---- p = exp(s/8), mask tail tile ----
    if (k0 + 64 <= L) {
#pragma unroll
      for (int n16 = 0; n16 < 4; ++n16) {
#pragma unroll
        for (int r = 0; r < 4; ++r) {
          const float p = __expf(sc[n16][r] * 0.125f);
          lsum[r] += p;
          Pw[(quad * 4 + r) * 72 + n16 * 16 + l15] = (bf16_t)p;
        }
      }
    } else {
#pragma unroll
      for (int n16 = 0; n16 < 4; ++n16) {
        const bool valid = (k0 + n16 * 16 + l15) < L;
#pragma unroll
        for (int r = 0; r < 4; ++r) {
          const float p = valid ? __expf(sc[n16][r] * 0.125f) : 0.f;
          lsum[r] += p;
          Pw[(quad * 4 + r) * 72 + n16 * 16 + l15] = (bf16_t)p;
        }
      }
    }

    // ---- O += P @ V ----
    const bf16x8 pf0 = *(const bf16x8*)(Pw + l15 * 72 + quad * 8);
    const bf16x8 pf1 = *(const bf16x8*)(Pw + l15 * 72 + 32 + quad * 8);
#pragma unroll
    for (int dt = 0; dt < 4; ++dt) {
      const int row = (dt * 16 + l15) * 32 + quad * 8;
      bf16x8 vf0 = *(const bf16x8*)(VsA + row);
      bf16x8 vf1 = *(const bf16x8*)(VsB + row);
      o[dt] = mfma_bf16(pf0, vf0, o[dt]);
      o[dt] = mfma_bf16(pf1, vf1, o[dt]);
    }
  }

  // ---- row-sum reduce, normalize, write [B,S,H*64] ----
  float inv[4];
#pragma unroll
  for (int r = 0; r < 4; ++r) {
    float t = lsum[r];
    t += __shfl_xor(t, 1, 64);
    t += __shfl_xor(t, 2, 64);
    t += __shfl_xor(t, 4, 64);
    t += __shfl_xor(t, 8, 64);
    inv[r] = 1.f / t;
  }
  const int qout = qt * 64 + wave * 16 + quad * 4;
#pragma unroll
  for (int dt = 0; dt < 4; ++dt) {
#pragma unroll
    for (int r = 0; r < 4; ++r) {
      const float v = o[dt][r] * inv[r];
      O[((size_t)(b * S_ + qout + r)) * (H_ * DH_) + h * DH_ + dt * 16 + l15] = (bf16_t)v;
    }
  }
}

// ---------------------------------------------------------------------------
extern "C" void kernel_launch(void* const* d_in, const int* in_sizes, int n_in,
                              void* d_out, int out_size, void* d_ws, size_t ws_size,
                              hipStream_t stream) {
  const float* queries = (const float*)d_in[0];
  const float* keys    = (const float*)d_in[1];
  const float* values  = (const float*)d_in[2];
  const float* Wq      = (const float*)d_in[3];
  const float* Wk      = (const float*)d_in[4];
  const float* Wv      = (const float*)d_in[5];
  const float* Wo      = (const float*)d_in[6];
  const int* valid_lens = (const int*)d_in[7];
  float* out = (float*)d_out;

  bf16_t* ws = (bf16_t*)d_ws;
  const size_t MB = 1024 * 1024;     // elements (bf16)
  bf16_t* WqT = ws + 0 * MB;
  bf16_t* WkT = ws + 1 * MB;
  bf16_t* WvT = ws + 2 * MB;
  bf16_t* WoT = ws + 3 * MB;
  bf16_t* Qc  = ws + 4 * MB;         // bf16 copies of inputs, 8M elems each
  bf16_t* Kc  = ws + 12 * MB;
  bf16_t* Vc  = ws + 20 * MB;
  bf16_t* Qb  = ws + 28 * MB;        // [B,H,S,64] projected
  bf16_t* Kb  = ws + 36 * MB;
  bf16_t* Vb  = ws + 44 * MB;
  bf16_t* VbT = ws + 52 * MB;        // [B,H,64,S] transposed V
  bf16_t* Ab  = ws + 60 * MB;        // [B,S,1024] attn out  (total 136 MB)

  // allow 144 KB dynamic LDS for the pipelined GEMMs (host API, capture-safe)
  (void)hipFuncSetAttribute((const void*)gemm_proj,
                            hipFuncAttributeMaxDynamicSharedMemorySize, LDS_BYTES);
  (void)hipFuncSetAttribute((const void*)gemm_out,
                            hipFuncAttributeMaxDynamicSharedMemorySize, LDS_BYTES);

  transpose4<<<dim3(16, 16, 4), 256, 0, stream>>>(Wq, Wk, Wv, Wo, WqT, WkT, WvT, WoT);

  convert_qkv<<<dim3(4096, 3), 256, 0, stream>>>(queries, keys, values, Qc, Kc, Vc);

  gemm_proj<<<dim3(256, 1, 3), 512, LDS_BYTES, stream>>>(Qc, Kc, Vc,
                                                         WqT, WkT, WvT,
                                                         Qb, Kb, Vb);

  transposeV<<<dim3(16, 128), 256, 0, stream>>>(Vb, VbT);

  attn64<<<dim3(16, 16, 8), 256, 0, stream>>>(Qb, Kb, VbT, valid_lens, Ab);

  gemm_out<<<dim3(256, 1, 1), 512, LDS_BYTES, stream>>>(Ab, WoT, out);
}

// Round 2
// 295.556 us; speedup vs baseline: 1.0284x; 1.0284x over previous
//
#include <hip/hip_runtime.h>
#include <hip/hip_bf16.h>
#include <stdint.h>

typedef __bf16 bf16_t;
typedef __bf16 bf16x8 __attribute__((ext_vector_type(8)));
typedef float f32x4 __attribute__((ext_vector_type(4)));

#define B_  8
#define S_  1024
#define D_  1024
#define H_  16
#define DH_ 64

static __device__ __forceinline__ f32x4 mfma_bf16(bf16x8 a, bf16x8 b, f32x4 c) {
  return __builtin_amdgcn_mfma_f32_16x16x32_bf16(a, b, c, 0, 0, 0);
}

// async global->LDS, 16 bytes per lane; LDS dest = wave-uniform base + lane*16
#define GLOAD_LDS16(g, l)                                                     \
  __builtin_amdgcn_global_load_lds(                                           \
      (const __attribute__((address_space(1))) void*)(g),                     \
      (__attribute__((address_space(3))) void*)(l), 16, 0, 0)

// ---------------------------------------------------------------------------
// Transpose four 1024x1024 f32 weights -> bf16 transposed: Wt[n][k] = W[k][n]
// grid (16,16,4), block 256
// ---------------------------------------------------------------------------
__global__ __launch_bounds__(256) void transpose4(
    const float* __restrict__ w0, const float* __restrict__ w1,
    const float* __restrict__ w2, const float* __restrict__ w3,
    bf16_t* __restrict__ t0, bf16_t* __restrict__ t1,
    bf16_t* __restrict__ t2, bf16_t* __restrict__ t3)
{
  __shared__ float tile[64][65];
  const float* src; bf16_t* dst;
  switch (blockIdx.z) {
    case 0: src = w0; dst = t0; break;
    case 1: src = w1; dst = t1; break;
    case 2: src = w2; dst = t2; break;
    default: src = w3; dst = t3; break;
  }
  const int tx = threadIdx.x & 63;
  const int ty = threadIdx.x >> 6;
  const int c0 = blockIdx.x * 64, r0 = blockIdx.y * 64;
#pragma unroll
  for (int r = ty; r < 64; r += 4)
    tile[r][tx] = src[(size_t)(r0 + r) * 1024 + c0 + tx];
  __syncthreads();
#pragma unroll
  for (int r = ty; r < 64; r += 4)
    dst[(size_t)(c0 + r) * 1024 + r0 + tx] = (bf16_t)tile[tx][r];
}

// ---------------------------------------------------------------------------
// Convert Q/K/V f32 -> bf16 (contiguous). grid (4096,3), block 256, 8 elem/thr.
// ---------------------------------------------------------------------------
__global__ __launch_bounds__(256) void convert_qkv(
    const float* __restrict__ q, const float* __restrict__ k,
    const float* __restrict__ v,
    bf16_t* __restrict__ qo, bf16_t* __restrict__ ko, bf16_t* __restrict__ vo)
{
  const float* src; bf16_t* dst;
  switch (blockIdx.y) {
    case 0: src = q; dst = qo; break;
    case 1: src = k; dst = ko; break;
    default: src = v; dst = vo; break;
  }
  const size_t i = ((size_t)blockIdx.x * 256 + threadIdx.x) * 8;
  float4 a = *(const float4*)(src + i);
  float4 b = *(const float4*)(src + i + 4);
  bf16x8 o;
  o[0] = (bf16_t)a.x; o[1] = (bf16_t)a.y; o[2] = (bf16_t)a.z; o[3] = (bf16_t)a.w;
  o[4] = (bf16_t)b.x; o[5] = (bf16_t)b.y; o[6] = (bf16_t)b.z; o[7] = (bf16_t)b.w;
  *(bf16x8*)(dst + i) = o;
}

// ---------------------------------------------------------------------------
// Transpose V: [B,H,S,64] -> [B,H,64,S].  grid (16, 128): x=s-tile, y=b*H+h.
// ---------------------------------------------------------------------------
__global__ __launch_bounds__(256) void transposeV(
    const bf16_t* __restrict__ src, bf16_t* __restrict__ dst)
{
  __shared__ bf16_t t[64 * 72];     // row stride 72 elems (144B, 16B-aligned)
  const size_t base = (size_t)blockIdx.y * (64 * 1024);
  const int s0 = blockIdx.x * 64;
#pragma unroll
  for (int it = 0; it < 2; ++it) {
    const int c = it * 256 + threadIdx.x;
    const int r = c >> 3, col8 = (c & 7) * 8;
    bf16x8 v = *(const bf16x8*)(src + base + (size_t)(s0 + r) * 64 + col8);
    *(bf16x8*)(t + r * 72 + col8) = v;
  }
  __syncthreads();
#pragma unroll
  for (int it = 0; it < 2; ++it) {
    const int c = it * 256 + threadIdx.x;
    const int d = c >> 3, sc8 = (c & 7) * 8;
    bf16x8 v;
#pragma unroll
    for (int j = 0; j < 8; ++j) v[j] = t[(sc8 + j) * 72 + d];
    *(bf16x8*)(dst + base + (size_t)d * 1024 + s0 + sc8) = v;
  }
}

// ---------------------------------------------------------------------------
// Pipelined GEMM core (T2+T3+T4+T5): C = A[M,K](bf16) @ Bt[N,K](bf16)^T
//   BM=256, BN=128, BK=64; 512 thr = 8 waves (4M x 2N), 64x64 out per wave.
//   3-stage LDS pipeline (144 KB dynamic), counted s_waitcnt vmcnt(12)
//   (never drains to 0 in the main loop); XOR slot-swizzle (slot ^= row&7)
//   applied as inverse-swizzled GLOBAL source + swizzled ds_read (rule #21).
//   XCD mapping (R1 fix): xcd = blockIdx.x%8 owns a CONTIGUOUS 4-M-tile slab
//   (1024 rows of A = 2 MB in its L2) x all 8 N-tiles (full B = 2 MB) ->
//   4 MB/XCD working set = L2 size; A never replicated across XCDs.
//   (R1 had tileN=x%8: A-panels fetched by all 8 XCDs -> FETCH 57->200 MB.)
// MODE: 0 = C f32 row-major; 1 = C bf16 scatter into [B,H,S,64].
// ---------------------------------------------------------------------------
#define BM_G 256
#define BN_G 128
#define BK_G 64
#define KDIM 1024
#define NK_G (KDIM / BK_G)                  // 16
#define ATILE (BM_G * BK_G)                 // 16384 elems (32 KB)
#define BTILE (BN_G * BK_G)                 // 8192 elems  (16 KB)
#define LDS_BYTES ((3 * (ATILE + BTILE)) * 2)  // 147456 B

template <int MODE>
__device__ __forceinline__ void gemm_core(
    const bf16_t* __restrict__ Ap, const bf16_t* __restrict__ Bp,
    void* __restrict__ Cp, bf16_t* smem)
{
  bf16_t* const As = smem;                  // 3 * ATILE
  bf16_t* const Bs = smem + 3 * ATILE;      // 3 * BTILE

  const int tid  = threadIdx.x;
  const int wv   = tid >> 6;
  const int lane = tid & 63;
  const int wm   = wv >> 1;                 // 0..3  (M position)
  const int wn   = wv & 1;                  // 0..1  (N position)
  const int quad = lane >> 4;
  const int l15  = lane & 15;

  // XCD-local A-slab mapping: xcd owns tileM in [xcd*4, xcd*4+4), all tileN.
  const int xcd   = blockIdx.x & 7;
  const int rblk  = blockIdx.x >> 3;        // 0..31
  const int tileM = xcd * 4 + (rblk & 3);
  const int tileN = rblk >> 2;              // 0..7

  // --- staging addressing -------------------------------------------------
  // Each GLOAD line: 512 thr x 16B = 8KB = 64 rows x 128B. Wave wv covers
  // rows [base + wv*8, +8); lane l -> row +(l>>3), LDS 16B-slot (l&7).
  // Inverse swizzle on the global side: slot s holds global slot s^(row&7).
  const int lr  = lane >> 3;                        // row within 8-row group
  const int swz = (((lane & 7) ^ lr) << 3);         // swizzled col (elems)
  const bf16_t* gA0 = Ap + (size_t)(tileM * BM_G + wv * 8 + lr) * KDIM + swz;
  const bf16_t* gB0 = Bp + (size_t)(tileN * BN_G + wv * 8 + lr) * KDIM + swz;
  const int lA0 = wv * 8 * BK_G;                    // wave-uniform LDS elems
  const int lB0 = wv * 8 * BK_G;

#define STAGE_TILE(koff, bA, bB) do {                                          \
    GLOAD_LDS16(gA0 + (koff),                       As + (bA) + lA0);          \
    GLOAD_LDS16(gA0 + (size_t)64  * KDIM + (koff),  As + (bA) + lA0 + 64*BK_G); \
    GLOAD_LDS16(gA0 + (size_t)128 * KDIM + (koff),  As + (bA) + lA0 + 128*BK_G);\
    GLOAD_LDS16(gA0 + (size_t)192 * KDIM + (koff),  As + (bA) + lA0 + 192*BK_G);\
    GLOAD_LDS16(gB0 + (koff),                       Bs + (bB) + lB0);          \
    GLOAD_LDS16(gB0 + (size_t)64  * KDIM + (koff),  Bs + (bB) + lB0 + 64*BK_G); \
  } while (0)

  f32x4 acc[4][4];
#pragma unroll
  for (int mi = 0; mi < 4; ++mi)
#pragma unroll
    for (int ni = 0; ni < 4; ++ni)
      acc[mi][ni] = (f32x4){0.f, 0.f, 0.f, 0.f};

  // prologue: tiles 0,1 -> bufs 0,1 (12 loads in flight)
  STAGE_TILE(0, 0, 0);
  STAGE_TILE(BK_G, ATILE, BTILE);

  int cbA = 0, cbB = 0;                    // compute-buffer elem offsets
  int sbA = 2 * ATILE, sbB = 2 * BTILE;    // stage-buffer elem offsets

  for (int t = 0; t < NK_G; ++t) {
    // stage tile t+2 into the buffer whose reads finished last iteration
    if (t + 2 < NK_G) STAGE_TILE((size_t)(t + 2) * BK_G, sbA, sbB);

    // counted wait: only tile t's 6 loads must land; t+1/t+2 stay in flight
    if (t < NK_G - 2)       asm volatile("s_waitcnt vmcnt(12)" ::: "memory");
    else if (t == NK_G - 2) asm volatile("s_waitcnt vmcnt(6)" ::: "memory");
    else                    asm volatile("s_waitcnt vmcnt(0)" ::: "memory");
    __builtin_amdgcn_s_barrier();
    asm volatile("" ::: "memory");         // no LDS-read hoist above barrier

    // frag reads: swizzled slot = (quad+4*kk) ^ (row&7); row&7 == l15&7
    bf16x8 af[2][4], bfr[2][4];
#pragma unroll
    for (int kk = 0; kk < 2; ++kk) {
      const int sl = (((quad + (kk << 2)) ^ (l15 & 7)) << 3);
#pragma unroll
      for (int mi = 0; mi < 4; ++mi)
        af[kk][mi] = *(const bf16x8*)(As + cbA + (wm * 64 + mi * 16 + l15) * BK_G + sl);
#pragma unroll
      for (int ni = 0; ni < 4; ++ni)
        bfr[kk][ni] = *(const bf16x8*)(Bs + cbB + (wn * 64 + ni * 16 + l15) * BK_G + sl);
    }
    __builtin_amdgcn_s_setprio(1);
#pragma unroll
    for (int kk = 0; kk < 2; ++kk)
#pragma unroll
      for (int mi = 0; mi < 4; ++mi)
#pragma unroll
        for (int ni = 0; ni < 4; ++ni)
          acc[mi][ni] = mfma_bf16(af[kk][mi], bfr[kk][ni], acc[mi][ni]);
    __builtin_amdgcn_s_setprio(0);

    asm volatile("" ::: "memory");         // no LDS-read sink below barrier
    __builtin_amdgcn_s_barrier();          // buf safe to overwrite next iter

    cbA += ATILE; if (cbA == 3 * ATILE) cbA = 0;
    cbB += BTILE; if (cbB == 3 * BTILE) cbB = 0;
    sbA += ATILE; if (sbA == 3 * ATILE) sbA = 0;
    sbB += BTILE; if (sbB == 3 * BTILE) sbB = 0;
  }
#undef STAGE_TILE

  // epilogue: C/D frag layout col=l15(N), row=quad*4+r(M)
#pragma unroll
  for (int mi = 0; mi < 4; ++mi) {
#pragma unroll
    for (int ni = 0; ni < 4; ++ni) {
#pragma unroll
      for (int r = 0; r < 4; ++r) {
        const int row = tileM * BM_G + wm * 64 + mi * 16 + quad * 4 + r;
        const int col = tileN * BN_G + wn * 64 + ni * 16 + l15;
        if (MODE == 0) {
          ((float*)Cp)[(size_t)row * 1024 + col] = acc[mi][ni][r];
        } else {
          const int b = row >> 10, s = row & 1023;
          const int h = col >> 6,  d = col & 63;
          ((bf16_t*)Cp)[(((size_t)(b * H_ + h) << 10) | s) * DH_ + d] =
              (bf16_t)acc[mi][ni][r];
        }
      }
    }
  }
}

// Projection GEMM: z selects {A,B,C}. grid (256,1,3), block 512, 144KB dyn LDS.
__global__ __launch_bounds__(512, 2) void gemm_proj(
    const bf16_t* __restrict__ A0, const bf16_t* __restrict__ A1, const bf16_t* __restrict__ A2,
    const bf16_t* __restrict__ B0, const bf16_t* __restrict__ B1, const bf16_t* __restrict__ B2,
    bf16_t* __restrict__ C0, bf16_t* __restrict__ C1, bf16_t* __restrict__ C2)
{
  extern __shared__ bf16_t smem[];
  const bf16_t* Ap; const bf16_t* Bp; bf16_t* Cp;
  if (blockIdx.z == 0)      { Ap = A0; Bp = B0; Cp = C0; }
  else if (blockIdx.z == 1) { Ap = A1; Bp = B1; Cp = C1; }
  else                      { Ap = A2; Bp = B2; Cp = C2; }
  gemm_core<1>(Ap, Bp, (void*)Cp, smem);
}

// Output GEMM: f32 row-major C. grid (256,1,1), block 512, 144KB dyn LDS.
__global__ __launch_bounds__(512, 2) void gemm_out(
    const bf16_t* __restrict__ Ap, const bf16_t* __restrict__ Bp,
    float* __restrict__ Cp)
{
  extern __shared__ bf16_t smem[];
  gemm_core<0>(Ap, Bp, (void*)Cp, smem);
}

// ---------------------------------------------------------------------------
// Flash attention v4: m97-shaped block-cooperative K-loop. (unchanged)
// ---------------------------------------------------------------------------
__global__ __launch_bounds__(256) void attn64(
    const bf16_t* __restrict__ Q,
    const bf16_t* __restrict__ Kv,
    const bf16_t* __restrict__ Vt,
    const int* __restrict__ valid_lens,
    bf16_t* __restrict__ O)
{
  const int h  = blockIdx.x;
  const int qt = blockIdx.y;
  const int b  = blockIdx.z;
  const int tid  = threadIdx.x;
  const int wave = tid >> 6;
  const int lane = tid & 63;
  const int quad = lane >> 4;
  const int l15  = lane & 15;

  const int L   = valid_lens[b];
  const int nkt = (L + 63) >> 6;

  const size_t base = ((size_t)(b * H_ + h)) * S_ * DH_;
  const bf16_t* Qp = Q  + base;
  const bf16_t* Kp = Kv + base;
  const bf16_t* Vp = Vt + base;     // [64][1024] per (b,h)

  __shared__ bf16_t KsA[64 * 32];   // K tile, d 0..31   [key][d]
  __shared__ bf16_t KsB[64 * 32];   // K tile, d 32..63
  __shared__ bf16_t VsA[64 * 32];   // V^T tile, keys 0..31  [d][key]
  __shared__ bf16_t VsB[64 * 32];   // V^T tile, keys 32..63
  __shared__ bf16_t Pb[4][16 * 72]; // per-wave P [q][key]
  bf16_t* const Pw = &Pb[wave][0];

  const int sr = tid >> 2;
  const int sj = (tid & 3) << 3;
  const int ldsOff = (wave * 64) * 8;      // wave-uniform LDS base offset

  const int qrow = qt * 64 + wave * 16 + l15;
  const bf16x8 qf0 = *(const bf16x8*)(Qp + (size_t)qrow * DH_ + quad * 8);
  const bf16x8 qf1 = *(const bf16x8*)(Qp + (size_t)qrow * DH_ + 32 + quad * 8);

  f32x4 o[4];
  float lsum[4];
#pragma unroll
  for (int r = 0; r < 4; ++r) {
    o[r] = (f32x4){0.f, 0.f, 0.f, 0.f};
    lsum[r] = 0.f;
  }

  for (int kt = 0; kt < nkt; ++kt) {
    const int k0 = kt * 64;

    __syncthreads();   // prior tile's LDS reads complete
    GLOAD_LDS16(Kp + (size_t)(k0 + sr) * DH_ + sj,      KsA + ldsOff);
    GLOAD_LDS16(Kp + (size_t)(k0 + sr) * DH_ + 32 + sj, KsB + ldsOff);
    GLOAD_LDS16(Vp + (size_t)sr * S_ + k0 + sj,         VsA + ldsOff);
    GLOAD_LDS16(Vp + (size_t)sr * S_ + k0 + 32 + sj,    VsB + ldsOff);
    __syncthreads();   // staging drained

    // ---- scores: S = Q K^T ----
    f32x4 sc[4];
#pragma unroll
    for (int n16 = 0; n16 < 4; ++n16) {
      const int row = (n16 * 16 + l15) * 32 + quad * 8;
      bf16x8 kf0 = *(const bf16x8*)(KsA + row);
      bf16x8 kf1 = *(const bf16x8*)(KsB + row);
      f32x4 s = (f32x4){0.f, 0.f, 0.f, 0.f};
      s = mfma_bf16(qf0, kf0, s);
      s = mfma_bf16(qf1, kf1, s);
      sc[n16] = s;
    }

    // ---- p = exp(s/8), mask tail tile ----
    if (k0 + 64 <= L) {
#pragma unroll
      for (int n16 = 0; n16 < 4; ++n16) {
#pragma unroll
        for (int r = 0; r < 4; ++r) {
          const float p = __expf(sc[n16][r] * 0.125f);
          lsum[r] += p;
          Pw[(quad * 4 + r) * 72 + n16 * 16 + l15] = (bf16_t)p;
        }
      }
    } else {
#pragma unroll
      for (int n16 = 0; n16 < 4; ++n16) {
        const bool valid = (k0 + n16 * 16 + l15) < L;
#pragma unroll
        for (int r = 0; r < 4; ++r) {
          const float p = valid ? __expf(sc[n16][r] * 0.125f) : 0.f;
          lsum[r] += p;
          Pw[(quad * 4 + r) * 72 + n16 * 16 + l15] = (bf16_t)p;
        }
      }
    }

    // ---- O += P @ V ----
    const bf16x8 pf0 = *(const bf16x8*)(Pw + l15 * 72 + quad * 8);
    const bf16x8 pf1 = *(const bf16x8*)(Pw + l15 * 72 + 32 + quad * 8);
#pragma unroll
    for (int dt = 0; dt < 4; ++dt) {
      const int row = (dt * 16 + l15) * 32 + quad * 8;
      bf16x8 vf0 = *(const bf16x8*)(VsA + row);
      bf16x8 vf1 = *(const bf16x8*)(VsB + row);
      o[dt] = mfma_bf16(pf0, vf0, o[dt]);
      o[dt] = mfma_bf16(pf1, vf1, o[dt]);
    }
  }

  // ---- row-sum reduce, normalize, write [B,S,H*64] ----
  float inv[4];
#pragma unroll
  for (int r = 0; r < 4; ++r) {
    float t = lsum[r];
    t += __shfl_xor(t, 1, 64);
    t += __shfl_xor(t, 2, 64);
    t += __shfl_xor(t, 4, 64);
    t += __shfl_xor(t, 8, 64);
    inv[r] = 1.f / t;
  }
  const int qout = qt * 64 + wave * 16 + quad * 4;
#pragma unroll
  for (int dt = 0; dt < 4; ++dt) {
#pragma unroll
    for (int r = 0; r < 4; ++r) {
      const float v = o[dt][r] * inv[r];
      O[((size_t)(b * S_ + qout + r)) * (H_ * DH_) + h * DH_ + dt * 16 + l15] = (bf16_t)v;
    }
  }
}

// ---------------------------------------------------------------------------
extern "C" void kernel_launch(void* const* d_in, const int* in_sizes, int n_in,
                              void* d_out, int out_size, void* d_ws, size_t ws_size,
                              hipStream_t stream) {
  const float* queries = (const float*)d_in[0];
  const float* keys    = (const float*)d_in[1];
  const float* values  = (const float*)d_in[2];
  const float* Wq      = (const float*)d_in[3];
  const float* Wk      = (const float*)d_in[4];
  const float* Wv      = (const float*)d_in[5];
  const float* Wo      = (const float*)d_in[6];
  const int* valid_lens = (const int*)d_in[7];
  float* out = (float*)d_out;

  bf16_t* ws = (bf16_t*)d_ws;
  const size_t MB = 1024 * 1024;     // elements (bf16)
  bf16_t* WqT = ws + 0 * MB;
  bf16_t* WkT = ws + 1 * MB;
  bf16_t* WvT = ws + 2 * MB;
  bf16_t* WoT = ws + 3 * MB;
  bf16_t* Qc  = ws + 4 * MB;         // bf16 copies of inputs, 8M elems each
  bf16_t* Kc  = ws + 12 * MB;
  bf16_t* Vc  = ws + 20 * MB;
  bf16_t* Qb  = ws + 28 * MB;        // [B,H,S,64] projected
  bf16_t* Kb  = ws + 36 * MB;
  bf16_t* Vb  = ws + 44 * MB;
  bf16_t* VbT = ws + 52 * MB;        // [B,H,64,S] transposed V
  bf16_t* Ab  = ws + 60 * MB;        // [B,S,1024] attn out  (total 136 MB)

  // allow 144 KB dynamic LDS for the pipelined GEMMs (host API, capture-safe)
  (void)hipFuncSetAttribute((const void*)gemm_proj,
                            hipFuncAttributeMaxDynamicSharedMemorySize, LDS_BYTES);
  (void)hipFuncSetAttribute((const void*)gemm_out,
                            hipFuncAttributeMaxDynamicSharedMemorySize, LDS_BYTES);

  transpose4<<<dim3(16, 16, 4), 256, 0, stream>>>(Wq, Wk, Wv, Wo, WqT, WkT, WvT, WoT);

  convert_qkv<<<dim3(4096, 3), 256, 0, stream>>>(queries, keys, values, Qc, Kc, Vc);

  gemm_proj<<<dim3(256, 1, 3), 512, LDS_BYTES, stream>>>(Qc, Kc, Vc,
                                                         WqT, WkT, WvT,
                                                         Qb, Kb, Vb);

  transposeV<<<dim3(16, 128), 256, 0, stream>>>(Vb, VbT);

  attn64<<<dim3(16, 16, 8), 256, 0, stream>>>(Qb, Kb, VbT, valid_lens, Ab);

  gemm_out<<<dim3(256, 1, 1), 512, LDS_BYTES, stream>>>(Ab, WoT, out);
}

// Round 4
// 288.827 us; speedup vs baseline: 1.0523x; 1.0233x over previous
//
#include <hip/hip_runtime.h>
#include <hip/hip_bf16.h>
#include <stdint.h>

typedef __bf16 bf16_t;
typedef __bf16 bf16x8 __attribute__((ext_vector_type(8)));
typedef float f32x4 __attribute__((ext_vector_type(4)));

#define B_  8
#define S_  1024
#define D_  1024
#define H_  16
#define DH_ 64

static __device__ __forceinline__ f32x4 mfma_bf16(bf16x8 a, bf16x8 b, f32x4 c) {
  return __builtin_amdgcn_mfma_f32_16x16x32_bf16(a, b, c, 0, 0, 0);
}

// async global->LDS, 16 bytes per lane; LDS dest = wave-uniform base + lane*16
#define GLOAD_LDS16(g, l)                                                     \
  __builtin_amdgcn_global_load_lds(                                           \
      (const __attribute__((address_space(1))) void*)(g),                     \
      (__attribute__((address_space(3))) void*)(l), 16, 0, 0)

// ---------------------------------------------------------------------------
// Transpose four 1024x1024 f32 weights -> bf16 transposed: Wt[n][k] = W[k][n]
// grid (16,16,4), block 256
// ---------------------------------------------------------------------------
__global__ __launch_bounds__(256) void transpose4(
    const float* __restrict__ w0, const float* __restrict__ w1,
    const float* __restrict__ w2, const float* __restrict__ w3,
    bf16_t* __restrict__ t0, bf16_t* __restrict__ t1,
    bf16_t* __restrict__ t2, bf16_t* __restrict__ t3)
{
  __shared__ float tile[64][65];
  const float* src; bf16_t* dst;
  switch (blockIdx.z) {
    case 0: src = w0; dst = t0; break;
    case 1: src = w1; dst = t1; break;
    case 2: src = w2; dst = t2; break;
    default: src = w3; dst = t3; break;
  }
  const int tx = threadIdx.x & 63;
  const int ty = threadIdx.x >> 6;
  const int c0 = blockIdx.x * 64, r0 = blockIdx.y * 64;
#pragma unroll
  for (int r = ty; r < 64; r += 4)
    tile[r][tx] = src[(size_t)(r0 + r) * 1024 + c0 + tx];
  __syncthreads();
#pragma unroll
  for (int r = ty; r < 64; r += 4)
    dst[(size_t)(c0 + r) * 1024 + r0 + tx] = (bf16_t)tile[tx][r];
}

// ---------------------------------------------------------------------------
// Convert Q/K/V f32 -> bf16 (contiguous). grid (4096,3), block 256, 8 elem/thr.
// ---------------------------------------------------------------------------
__global__ __launch_bounds__(256) void convert_qkv(
    const float* __restrict__ q, const float* __restrict__ k,
    const float* __restrict__ v,
    bf16_t* __restrict__ qo, bf16_t* __restrict__ ko, bf16_t* __restrict__ vo)
{
  const float* src; bf16_t* dst;
  switch (blockIdx.y) {
    case 0: src = q; dst = qo; break;
    case 1: src = k; dst = ko; break;
    default: src = v; dst = vo; break;
  }
  const size_t i = ((size_t)blockIdx.x * 256 + threadIdx.x) * 8;
  float4 a = *(const float4*)(src + i);
  float4 b = *(const float4*)(src + i + 4);
  bf16x8 o;
  o[0] = (bf16_t)a.x; o[1] = (bf16_t)a.y; o[2] = (bf16_t)a.z; o[3] = (bf16_t)a.w;
  o[4] = (bf16_t)b.x; o[5] = (bf16_t)b.y; o[6] = (bf16_t)b.z; o[7] = (bf16_t)b.w;
  *(bf16x8*)(dst + i) = o;
}

// ---------------------------------------------------------------------------
// Transpose V: [B,H,S,64] -> [B,H,64,S].  grid (16, 128): x=s-tile, y=b*H+h.
// ---------------------------------------------------------------------------
__global__ __launch_bounds__(256) void transposeV(
    const bf16_t* __restrict__ src, bf16_t* __restrict__ dst)
{
  __shared__ bf16_t t[64 * 72];     // row stride 72 elems (144B, 16B-aligned)
  const size_t base = (size_t)blockIdx.y * (64 * 1024);
  const int s0 = blockIdx.x * 64;
#pragma unroll
  for (int it = 0; it < 2; ++it) {
    const int c = it * 256 + threadIdx.x;
    const int r = c >> 3, col8 = (c & 7) * 8;
    bf16x8 v = *(const bf16x8*)(src + base + (size_t)(s0 + r) * 64 + col8);
    *(bf16x8*)(t + r * 72 + col8) = v;
  }
  __syncthreads();
#pragma unroll
  for (int it = 0; it < 2; ++it) {
    const int c = it * 256 + threadIdx.x;
    const int d = c >> 3, sc8 = (c & 7) * 8;
    bf16x8 v;
#pragma unroll
    for (int j = 0; j < 8; ++j) v[j] = t[(sc8 + j) * 72 + d];
    *(bf16x8*)(dst + base + (size_t)d * 1024 + s0 + sc8) = v;
  }
}

// ---------------------------------------------------------------------------
// Pipelined GEMM core (T2+T3+T4+T5, fine-phase): C = A[M,K] @ Bt[N,K]^T bf16
//   BM=256, BN=128, BK=64; 512 thr = 8 waves (4M x 2N), 64x64 out per wave.
//   TRUE per-phase interleave (m201 template). 2 phases per K-tile,
//   16 MFMA each: {ds_read subtile + 3 gload_lds -> barrier -> lgkmcnt(0) ->
//   setprio(1) 16xMFMA setprio(0) -> [vmcnt(6) at phase B] -> barrier}.
//   B-frags read once in phase A, reused from registers in phase B.
//   vmcnt(6): next tile's 6 loads landed, t+2's 6 stay in flight (never 0).
//   XCD mapping: xcd = blockIdx.x%8 owns a contiguous 4-M-tile slab (2 MB A)
//   x all 8 N-tiles (2 MB B) = 4 MB/XCD = L2 (FETCH at 49 MB minimum, R2).
//   XOR slot-swizzle via inverse-swizzled global source (rule #21), 0 bank
//   conflicts (R1-verified).
// MODE: 0 = C f32 row-major; 1 = C bf16 scatter into [B,H,S,64].
// ---------------------------------------------------------------------------
#define BM_G 256
#define BN_G 128
#define BK_G 64
#define KDIM 1024
#define NK_G (KDIM / BK_G)                  // 16
#define ATILE (BM_G * BK_G)                 // 16384 elems (32 KB)
#define BTILE (BN_G * BK_G)                 // 8192 elems  (16 KB)
#define LDS_BYTES ((3 * (ATILE + BTILE)) * 2)  // 147456 B

template <int MODE>
__device__ __forceinline__ void gemm_core(
    const bf16_t* __restrict__ Ap, const bf16_t* __restrict__ Bp,
    void* __restrict__ Cp, bf16_t* smem)
{
  bf16_t* const As = smem;                  // 3 * ATILE
  bf16_t* const Bs = smem + 3 * ATILE;      // 3 * BTILE

  const int tid  = threadIdx.x;
  const int wv   = tid >> 6;
  const int lane = tid & 63;
  const int wm   = wv >> 1;                 // 0..3  (M position)
  const int wn   = wv & 1;                  // 0..1  (N position)
  const int quad = lane >> 4;
  const int l15  = lane & 15;

  // XCD-local A-slab mapping: xcd owns tileM in [xcd*4, xcd*4+4), all tileN.
  const int xcd   = blockIdx.x & 7;
  const int rblk  = blockIdx.x >> 3;        // 0..31
  const int tileM = xcd * 4 + (rblk & 3);
  const int tileN = rblk >> 2;              // 0..7

  // --- staging addressing -------------------------------------------------
  // Each GLOAD line: 512 thr x 16B = 8KB = 64 rows x 128B. Wave wv covers
  // rows [base + wv*8, +8); lane l -> row +(l>>3), LDS 16B-slot (l&7).
  // Inverse swizzle on the global side: slot s holds global slot s^(row&7).
  const int lr  = lane >> 3;                        // row within 8-row group
  const int swz = (((lane & 7) ^ lr) << 3);         // swizzled col (elems)
  const bf16_t* gA0 = Ap + (size_t)(tileM * BM_G + wv * 8 + lr) * KDIM + swz;
  const bf16_t* gB0 = Bp + (size_t)(tileN * BN_G + wv * 8 + lr) * KDIM + swz;
  const int lA0 = wv * 8 * BK_G;                    // wave-uniform LDS elems
  const int lB0 = wv * 8 * BK_G;

  f32x4 acc[4][4];
#pragma unroll
  for (int mi = 0; mi < 4; ++mi)
#pragma unroll
    for (int ni = 0; ni < 4; ++ni)
      acc[mi][ni] = (f32x4){0.f, 0.f, 0.f, 0.f};

  // prologue: tiles 0,1 -> bufs 0,1 (12 loads); wait tile 0 (6 stay in flight)
#define STAGE_TILE(koff, bA, bB) do {                                          \
    GLOAD_LDS16(gA0 + (koff),                       As + (bA) + lA0);          \
    GLOAD_LDS16(gA0 + (size_t)64  * KDIM + (koff),  As + (bA) + lA0 + 64*BK_G); \
    GLOAD_LDS16(gA0 + (size_t)128 * KDIM + (koff),  As + (bA) + lA0 + 128*BK_G);\
    GLOAD_LDS16(gA0 + (size_t)192 * KDIM + (koff),  As + (bA) + lA0 + 192*BK_G);\
    GLOAD_LDS16(gB0 + (koff),                       Bs + (bB) + lB0);          \
    GLOAD_LDS16(gB0 + (size_t)64  * KDIM + (koff),  Bs + (bB) + lB0 + 64*BK_G); \
  } while (0)

  STAGE_TILE(0, 0, 0);
  STAGE_TILE(BK_G, ATILE, BTILE);
  asm volatile("s_waitcnt vmcnt(6)" ::: "memory");
  __builtin_amdgcn_s_barrier();

  int cbA = 0, cbB = 0;                    // compute-buffer elem offsets
  int sbA = 2 * ATILE, sbB = 2 * BTILE;    // stage-buffer elem offsets

  for (int t = 0; t < NK_G; ++t) {
    const bool havePf = (t + 2 < NK_G);
    const size_t koff = (size_t)(t + 2) * BK_G;

    // =============== PHASE A: mi 0,1 x ni 0..3 x kk 0,1 ===============
    bf16x8 afA[2][2], bfr[2][4];
#pragma unroll
    for (int kk = 0; kk < 2; ++kk) {
      const int sl = (((quad + (kk << 2)) ^ (l15 & 7)) << 3);
#pragma unroll
      for (int mi = 0; mi < 2; ++mi)
        afA[kk][mi] = *(const bf16x8*)(As + cbA + (wm * 64 + mi * 16 + l15) * BK_G + sl);
#pragma unroll
      for (int ni = 0; ni < 4; ++ni)
        bfr[kk][ni] = *(const bf16x8*)(Bs + cbB + (wn * 64 + ni * 16 + l15) * BK_G + sl);
    }
    if (havePf) {
      GLOAD_LDS16(gA0 + koff,                       As + sbA + lA0);
      GLOAD_LDS16(gA0 + (size_t)64  * KDIM + koff,  As + sbA + lA0 + 64 * BK_G);
      GLOAD_LDS16(gA0 + (size_t)128 * KDIM + koff,  As + sbA + lA0 + 128 * BK_G);
    }
    asm volatile("" ::: "memory");
    __builtin_amdgcn_s_barrier();
    asm volatile("s_waitcnt lgkmcnt(0)" ::: "memory");
    __builtin_amdgcn_sched_barrier(0);
    __builtin_amdgcn_s_setprio(1);
#pragma unroll
    for (int kk = 0; kk < 2; ++kk)
#pragma unroll
      for (int mi = 0; mi < 2; ++mi)
#pragma unroll
        for (int ni = 0; ni < 4; ++ni)
          acc[mi][ni] = mfma_bf16(afA[kk][mi], bfr[kk][ni], acc[mi][ni]);
    __builtin_amdgcn_s_setprio(0);
    __builtin_amdgcn_sched_barrier(0);
    asm volatile("" ::: "memory");
    __builtin_amdgcn_s_barrier();

    // =============== PHASE B: mi 2,3 x ni 0..3 x kk 0,1 ===============
    bf16x8 afB[2][2];
#pragma unroll
    for (int kk = 0; kk < 2; ++kk) {
      const int sl = (((quad + (kk << 2)) ^ (l15 & 7)) << 3);
#pragma unroll
      for (int mi = 0; mi < 2; ++mi)
        afB[kk][mi] = *(const bf16x8*)(As + cbA + (wm * 64 + (mi + 2) * 16 + l15) * BK_G + sl);
    }
    if (havePf) {
      GLOAD_LDS16(gA0 + (size_t)192 * KDIM + koff,  As + sbA + lA0 + 192 * BK_G);
      GLOAD_LDS16(gB0 + koff,                       Bs + sbB + lB0);
      GLOAD_LDS16(gB0 + (size_t)64  * KDIM + koff,  Bs + sbB + lB0 + 64 * BK_G);
    }
    asm volatile("" ::: "memory");
    __builtin_amdgcn_s_barrier();
    asm volatile("s_waitcnt lgkmcnt(0)" ::: "memory");
    __builtin_amdgcn_sched_barrier(0);
    __builtin_amdgcn_s_setprio(1);
#pragma unroll
    for (int kk = 0; kk < 2; ++kk)
#pragma unroll
      for (int mi = 0; mi < 2; ++mi)
#pragma unroll
        for (int ni = 0; ni < 4; ++ni)
          acc[mi + 2][ni] = mfma_bf16(afB[kk][mi], bfr[kk][ni], acc[mi + 2][ni]);
    __builtin_amdgcn_s_setprio(0);
    __builtin_amdgcn_sched_barrier(0);
    // counted wait for NEXT tile's buffer (t+2's 6 loads stay in flight)
    if (havePf)             asm volatile("s_waitcnt vmcnt(6)" ::: "memory");
    else if (t + 1 < NK_G)  asm volatile("s_waitcnt vmcnt(0)" ::: "memory");
    asm volatile("" ::: "memory");
    __builtin_amdgcn_s_barrier();

    cbA += ATILE; if (cbA == 3 * ATILE) cbA = 0;
    cbB += BTILE; if (cbB == 3 * BTILE) cbB = 0;
    sbA += ATILE; if (sbA == 3 * ATILE) sbA = 0;
    sbB += BTILE; if (sbB == 3 * BTILE) sbB = 0;
  }
#undef STAGE_TILE

  // epilogue: C/D frag layout col=l15(N), row=quad*4+r(M)
#pragma unroll
  for (int mi = 0; mi < 4; ++mi) {
#pragma unroll
    for (int ni = 0; ni < 4; ++ni) {
#pragma unroll
      for (int r = 0; r < 4; ++r) {
        const int row = tileM * BM_G + wm * 64 + mi * 16 + quad * 4 + r;
        const int col = tileN * BN_G + wn * 64 + ni * 16 + l15;
        if (MODE == 0) {
          ((float*)Cp)[(size_t)row * 1024 + col] = acc[mi][ni][r];
        } else {
          const int b = row >> 10, s = row & 1023;
          const int h = col >> 6,  d = col & 63;
          ((bf16_t*)Cp)[(((size_t)(b * H_ + h) << 10) | s) * DH_ + d] =
              (bf16_t)acc[mi][ni][r];
        }
      }
    }
  }
}

// Projection GEMM: z selects {A,B,C}. grid (256,1,3), block 512, 144KB dyn LDS.
__global__ __launch_bounds__(512, 2) void gemm_proj(
    const bf16_t* __restrict__ A0, const bf16_t* __restrict__ A1, const bf16_t* __restrict__ A2,
    const bf16_t* __restrict__ B0, const bf16_t* __restrict__ B1, const bf16_t* __restrict__ B2,
    bf16_t* __restrict__ C0, bf16_t* __restrict__ C1, bf16_t* __restrict__ C2)
{
  extern __shared__ bf16_t smem[];
  const bf16_t* Ap; const bf16_t* Bp; bf16_t* Cp;
  if (blockIdx.z == 0)      { Ap = A0; Bp = B0; Cp = C0; }
  else if (blockIdx.z == 1) { Ap = A1; Bp = B1; Cp = C1; }
  else                      { Ap = A2; Bp = B2; Cp = C2; }
  gemm_core<1>(Ap, Bp, (void*)Cp, smem);
}

// Output GEMM: f32 row-major C. grid (256,1,1), block 512, 144KB dyn LDS.
__global__ __launch_bounds__(512, 2) void gemm_out(
    const bf16_t* __restrict__ Ap, const bf16_t* __restrict__ Bp,
    float* __restrict__ Cp)
{
  extern __shared__ bf16_t smem[];
  gemm_core<0>(Ap, Bp, (void*)Cp, smem);
}

// ---------------------------------------------------------------------------
// Flash attention v4: m97-shaped block-cooperative K-loop. (unchanged)
// ---------------------------------------------------------------------------
__global__ __launch_bounds__(256) void attn64(
    const bf16_t* __restrict__ Q,
    const bf16_t* __restrict__ Kv,
    const bf16_t* __restrict__ Vt,
    const int* __restrict__ valid_lens,
    bf16_t* __restrict__ O)
{
  const int h  = blockIdx.x;
  const int qt = blockIdx.y;
  const int b  = blockIdx.z;
  const int tid  = threadIdx.x;
  const int wave = tid >> 6;
  const int lane = tid & 63;
  const int quad = lane >> 4;
  const int l15  = lane & 15;

  const int L   = valid_lens[b];
  const int nkt = (L + 63) >> 6;

  const size_t base = ((size_t)(b * H_ + h)) * S_ * DH_;
  const bf16_t* Qp = Q  + base;
  const bf16_t* Kp = Kv + base;
  const bf16_t* Vp = Vt + base;     // [64][1024] per (b,h)

  __shared__ bf16_t KsA[64 * 32];   // K tile, d 0..31   [key][d]
  __shared__ bf16_t KsB[64 * 32];   // K tile, d 32..63
  __shared__ bf16_t VsA[64 * 32];   // V^T tile, keys 0..31  [d][key]
  __shared__ bf16_t VsB[64 * 32];   // V^T tile, keys 32..63
  __shared__ bf16_t Pb[4][16 * 72]; // per-wave P [q][key]
  bf16_t* const Pw = &Pb[wave][0];

  const int sr = tid >> 2;
  const int sj = (tid & 3) << 3;
  const int ldsOff = (wave * 64) * 8;      // wave-uniform LDS base offset

  const int qrow = qt * 64 + wave * 16 + l15;
  const bf16x8 qf0 = *(const bf16x8*)(Qp + (size_t)qrow * DH_ + quad * 8);
  const bf16x8 qf1 = *(const bf16x8*)(Qp + (size_t)qrow * DH_ + 32 + quad * 8);

  f32x4 o[4];
  float lsum[4];
#pragma unroll
  for (int r = 0; r < 4; ++r) {
    o[r] = (f32x4){0.f, 0.f, 0.f, 0.f};
    lsum[r] = 0.f;
  }

  for (int kt = 0; kt < nkt; ++kt) {
    const int k0 = kt * 64;

    __syncthreads();   // prior tile's LDS reads complete
    GLOAD_LDS16(Kp + (size_t)(k0 + sr) * DH_ + sj,      KsA + ldsOff);
    GLOAD_LDS16(Kp + (size_t)(k0 + sr) * DH_ + 32 + sj, KsB + ldsOff);
    GLOAD_LDS16(Vp + (size_t)sr * S_ + k0 + sj,         VsA + ldsOff);
    GLOAD_LDS16(Vp + (size_t)sr * S_ + k0 + 32 + sj,    VsB + ldsOff);
    __syncthreads();   // staging drained

    // ---- scores: S = Q K^T ----
    f32x4 sc[4];
#pragma unroll
    for (int n16 = 0; n16 < 4; ++n16) {
      const int row = (n16 * 16 + l15) * 32 + quad * 8;
      bf16x8 kf0 = *(const bf16x8*)(KsA + row);
      bf16x8 kf1 = *(const bf16x8*)(KsB + row);
      f32x4 s = (f32x4){0.f, 0.f, 0.f, 0.f};
      s = mfma_bf16(qf0, kf0, s);
      s = mfma_bf16(qf1, kf1, s);
      sc[n16] = s;
    }

    // ---- p = exp(s/8), mask tail tile ----
    if (k0 + 64 <= L) {
#pragma unroll
      for (int n16 = 0; n16 < 4; ++n16) {
#pragma unroll
        for (int r = 0; r < 4; ++r) {
          const float p = __expf(sc[n16][r] * 0.125f);
          lsum[r] += p;
          Pw[(quad * 4 + r) * 72 + n16 * 16 + l15] = (bf16_t)p;
        }
      }
    } else {
#pragma unroll
      for (int n16 = 0; n16 < 4; ++n16) {
        const bool valid = (k0 + n16 * 16 + l15) < L;
#pragma unroll
        for (int r = 0; r < 4; ++r) {
          const float p = valid ? __expf(sc[n16][r] * 0.125f) : 0.f;
          lsum[r] += p;
          Pw[(quad * 4 + r) * 72 + n16 * 16 + l15] = (bf16_t)p;
        }
      }
    }

    // ---- O += P @ V ----
    const bf16x8 pf0 = *(const bf16x8*)(Pw + l15 * 72 + quad * 8);
    const bf16x8 pf1 = *(const bf16x8*)(Pw + l15 * 72 + 32 + quad * 8);
#pragma unroll
    for (int dt = 0; dt < 4; ++dt) {
      const int row = (dt * 16 + l15) * 32 + quad * 8;
      bf16x8 vf0 = *(const bf16x8*)(VsA + row);
      bf16x8 vf1 = *(const bf16x8*)(VsB + row);
      o[dt] = mfma_bf16(pf0, vf0, o[dt]);
      o[dt] = mfma_bf16(pf1, vf1, o[dt]);
    }
  }

  // ---- row-sum reduce, normalize, write [B,S,H*64] ----
  float inv[4];
#pragma unroll
  for (int r = 0; r < 4; ++r) {
    float t = lsum[r];
    t += __shfl_xor(t, 1, 64);
    t += __shfl_xor(t, 2, 64);
    t += __shfl_xor(t, 4, 64);
    t += __shfl_xor(t, 8, 64);
    inv[r] = 1.f / t;
  }
  const int qout = qt * 64 + wave * 16 + quad * 4;
#pragma unroll
  for (int dt = 0; dt < 4; ++dt) {
#pragma unroll
    for (int r = 0; r < 4; ++r) {
      const float v = o[dt][r] * inv[r];
      O[((size_t)(b * S_ + qout + r)) * (H_ * DH_) + h * DH_ + dt * 16 + l15] = (bf16_t)v;
    }
  }
}

// ---------------------------------------------------------------------------
extern "C" void kernel_launch(void* const* d_in, const int* in_sizes, int n_in,
                              void* d_out, int out_size, void* d_ws, size_t ws_size,
                              hipStream_t stream) {
  const float* queries = (const float*)d_in[0];
  const float* keys    = (const float*)d_in[1];
  const float* values  = (const float*)d_in[2];
  const float* Wq      = (const float*)d_in[3];
  const float* Wk      = (const float*)d_in[4];
  const float* Wv      = (const float*)d_in[5];
  const float* Wo      = (const float*)d_in[6];
  const int* valid_lens = (const int*)d_in[7];
  float* out = (float*)d_out;

  bf16_t* ws = (bf16_t*)d_ws;
  const size_t MB = 1024 * 1024;     // elements (bf16)
  bf16_t* WqT = ws + 0 * MB;
  bf16_t* WkT = ws + 1 * MB;
  bf16_t* WvT = ws + 2 * MB;
  bf16_t* WoT = ws + 3 * MB;
  bf16_t* Qc  = ws + 4 * MB;         // bf16 copies of inputs, 8M elems each
  bf16_t* Kc  = ws + 12 * MB;
  bf16_t* Vc  = ws + 20 * MB;
  bf16_t* Qb  = ws + 28 * MB;        // [B,H,S,64] projected
  bf16_t* Kb  = ws + 36 * MB;
  bf16_t* Vb  = ws + 44 * MB;
  bf16_t* VbT = ws + 52 * MB;        // [B,H,64,S] transposed V
  bf16_t* Ab  = ws + 60 * MB;        // [B,S,1024] attn out  (total 136 MB)

  // allow 144 KB dynamic LDS for the pipelined GEMMs (host API, capture-safe)
  (void)hipFuncSetAttribute((const void*)gemm_proj,
                            hipFuncAttributeMaxDynamicSharedMemorySize, LDS_BYTES);
  (void)hipFuncSetAttribute((const void*)gemm_out,
                            hipFuncAttributeMaxDynamicSharedMemorySize, LDS_BYTES);

  transpose4<<<dim3(16, 16, 4), 256, 0, stream>>>(Wq, Wk, Wv, Wo, WqT, WkT, WvT, WoT);

  convert_qkv<<<dim3(4096, 3), 256, 0, stream>>>(queries, keys, values, Qc, Kc, Vc);

  gemm_proj<<<dim3(256, 1, 3), 512, LDS_BYTES, stream>>>(Qc, Kc, Vc,
                                                         WqT, WkT, WvT,
                                                         Qb, Kb, Vb);

  transposeV<<<dim3(16, 128), 256, 0, stream>>>(Vb, VbT);

  attn64<<<dim3(16, 16, 8), 256, 0, stream>>>(Qb, Kb, VbT, valid_lens, Ab);

  gemm_out<<<dim3(256, 1, 1), 512, LDS_BYTES, stream>>>(Ab, WoT, out);
}